// Round 8
// baseline (125.337 us; speedup 1.0000x reference)
//
#include <hip/hip_runtime.h>

#define C2  2.8853900817779268f   // 2*log2(e)
#define L2E 1.4426950408889634f   // log2(e)

typedef float float2v __attribute__((ext_vector_type(2)));

__device__ __forceinline__ float2v pk_fma(float2v a, float2v b, float2v c) {
  float2v d;
  asm("v_pk_fma_f32 %0, %1, %2, %3" : "=v"(d) : "v"(a), "v"(b), "v"(c));
  return d;
}
// d.lo = a.lo*b.lo + c.lo ; d.hi = a.hi*b.lo + c.hi   (broadcast b.lo)
__device__ __forceinline__ float2v pk_fma_bl(float2v a, float2v b, float2v c) {
  float2v d;
  asm("v_pk_fma_f32 %0, %1, %2, %3 op_sel:[0,0,0] op_sel_hi:[1,0,1]"
      : "=v"(d) : "v"(a), "v"(b), "v"(c));
  return d;
}
// d.lo = a.lo*b.hi + c.lo ; d.hi = a.hi*b.hi + c.hi   (broadcast b.hi)
__device__ __forceinline__ float2v pk_fma_bh(float2v a, float2v b, float2v c) {
  float2v d;
  asm("v_pk_fma_f32 %0, %1, %2, %3 op_sel:[0,1,0] op_sel_hi:[1,1,1]"
      : "=v"(d) : "v"(a), "v"(b), "v"(c));
  return d;
}

// ---------------- Projection (outputs PRE-SCALED by C2):
// block = 16 rows x 16 d; grid = 384 row-groups x 4 d-groups = 1536 blocks, 16KB LDS.
__global__ __launch_bounds__(256) void proj_kernel(
    const float* __restrict__ inputs, const float* __restrict__ memory,
    const float* __restrict__ W_in, const float* __restrict__ b_in,
    const float* __restrict__ W_mem,
    float* __restrict__ in_item, float* __restrict__ mem_itemT)
{
  const int NIN = 2048;
  int blk = blockIdx.x;
  int dg = blk & 3;
  int r0 = (blk >> 2) * 16;
  int tid = threadIdx.x;
  int dl = tid & 15;            // d within group
  int rw = tid >> 4;            // row within block (0..15)
  int d  = dg * 16 + dl;

  __shared__ float4 wlds[16][64];   // W rows [dg*16 .. dg*16+16), swizzled

  bool is_in = (r0 < NIN);
  const float* Wsel  = is_in ? W_in  : W_mem;
  const float* Abase = is_in ? inputs : memory;
  int ar0 = is_in ? r0 : r0 - NIN;

  const float4* Wv = reinterpret_cast<const float4*>(Wsel + (size_t)dg * 16 * 256);
  #pragma unroll
  for (int u = 0; u < 4; ++u) {
    int e = tid + u * 256;       // 0..1023
    int j = e >> 6, k4 = e & 63;
    wlds[j][k4 ^ (j & 7)] = Wv[e];
  }
  float bias = is_in ? b_in[d] : 0.f;
  __syncthreads();

  const float4* A0 = reinterpret_cast<const float4*>(Abase + (size_t)(ar0 + rw) * 256);
  float2v acc = {0.f, 0.f};
  #pragma unroll 8
  for (int k4 = 0; k4 < 64; ++k4) {
    float4 w = wlds[dl][k4 ^ (dl & 7)];
    float4 a = A0[k4];
    acc = pk_fma(float2v{a.x, a.y}, float2v{w.x, w.y}, acc);
    acc = pk_fma(float2v{a.z, a.w}, float2v{w.z, w.w}, acc);
  }
  float val = (acc.x + acc.y + bias) * C2;
  int row = ar0 + rw;
  if (is_in) {
    in_item[(size_t)row * 64 + d] = val;
  } else {
    int b_ = row >> 10, m = row & 1023;
    mem_itemT[((size_t)(b_ * 16 + (d >> 2)) * 1024 + m) * 4 + (d & 3)] = val;
  }
}

// ---------------- Fused score+softmax+PV over a Tm slice.
// 256 threads (4 waves), TI=4 rows, MT=64 tiles, single 16KB tile buffer,
// register prefetch, 2 barriers/tile. ~18KB LDS -> 8 blocks/CU.
__global__ __launch_bounds__(256, 8) void attn_kernel(
    const float* __restrict__ in_item,   // (B,Ti,64), pre-scaled
    const float* __restrict__ mem_itemT, // (B,16,Tm,4), pre-scaled, d-major
    const float* __restrict__ memory,    // (B,Tm,256)
    const int* __restrict__ in_len, const int* __restrict__ mem_len,
    const float* __restrict__ W_final,   // (64)
    float* __restrict__ o_part,          // (nsplit, B*Ti, 256)
    float* __restrict__ psum_part,       // (nsplit, B*Ti)
    int m_count)
{
  const int Ti = 512, Tm = 1024, DM = 256;
  const int TI = 4, MT = 64;
  const int NT = m_count >> 6;
  int lin = blockIdx.x;
  int b, z, it;
  if (m_count == 512) { b = lin & 3; z = (lin >> 2) & 1; it = lin >> 3; }
  else                { b = lin & 3; z = 0;              it = lin >> 2; }
  int i0 = it * TI;
  int m_begin = z * m_count;
  int tid = threadIdx.x;

  __shared__ float4 mt[16 * 64];     // mem_item tile, 16KB, swizzled
  __shared__ float4 pt4[2][64];      // p transposed, dbuf, 2KB
  __shared__ float  red[4];

  const int s_ii = __builtin_amdgcn_readfirstlane(tid >> 6);  // wave-uniform row
  const int s_ml = tid & 63;
  const int dq = tid & 63, wv_ = tid >> 6;

  float4 qreg[16];   // wave-uniform -> SGPRs
  {
    const float4* qrow = reinterpret_cast<const float4*>(
        in_item + ((size_t)b * Ti + i0 + s_ii) * 64);
    #pragma unroll
    for (int j = 0; j < 16; ++j) qreg[j] = qrow[j];
  }

  float Wsum = 0.f;
  #pragma unroll
  for (int j = 0; j < 64; ++j) Wsum += W_final[j];   // uniform -> s_loads
  const float c1 = L2E * Wsum;
  const float4* Wf4 = reinterpret_cast<const float4*>(W_final);

  int ilen = in_len[b], mlen = mem_len[b];
  const bool row_valid = (i0 + s_ii) < ilen;

  const float4* mT4 = reinterpret_cast<const float4*>(mem_itemT);
  const int bb16 = b * 16;
  const float* memb = memory + (size_t)b * Tm * DM;

  float psum = 0.f;
  float2v a0x = {0,0}, a0z = {0,0}, a1x = {0,0}, a1z = {0,0};
  float2v a2x = {0,0}, a2z = {0,0}, a3x = {0,0}, a3z = {0,0};

  // ---- prologue: stage tile 0 (16KB: 4 float4 per thread) ----
  #pragma unroll
  for (int u = 0; u < 4; ++u) {
    int e = tid + u * 256;
    int d4 = e >> 6, mm = e & 63;
    mt[d4 * 64 + (mm ^ (d4 & 7))] = mT4[(size_t)(bb16 + d4) * 1024 + m_begin + mm];
  }
  __syncthreads();

  #pragma unroll 1
  for (int t = 0; t < NT; ++t) {
    int m0 = m_begin + t * MT;

    // ---- issue next-tile global loads early (hide under score) ----
    float4 stg0, stg1, stg2, stg3;
    bool do_stage = (t + 1 < NT);
    if (do_stage) {
      int m0n = m0 + MT - m_begin;
      int e0 = tid, e1 = tid + 256, e2 = tid + 512, e3 = tid + 768;
      stg0 = mT4[(size_t)(bb16 + (e0 >> 6)) * 1024 + m_begin + m0n + (e0 & 63)];
      stg1 = mT4[(size_t)(bb16 + (e1 >> 6)) * 1024 + m_begin + m0n + (e1 & 63)];
      stg2 = mT4[(size_t)(bb16 + (e2 >> 6)) * 1024 + m_begin + m0n + (e2 & 63)];
      stg3 = mT4[(size_t)(bb16 + (e3 >> 6)) * 1024 + m_begin + m0n + (e3 & 63)];
    }

    // ---- score: LDS reads, q/w uniform ----
    {
      float4 S4 = make_float4(0.f, 0.f, 0.f, 0.f);
      #pragma unroll
      for (int d4 = 0; d4 < 16; ++d4) {
        float4 mv = mt[d4 * 64 + (s_ml ^ (d4 & 7))];
        float4 qv = qreg[d4];
        float4 w  = Wf4[d4];
        S4.x = fmaf(w.x, __builtin_amdgcn_rcpf(1.0f + __builtin_amdgcn_exp2f(qv.x + mv.x)), S4.x);
        S4.y = fmaf(w.y, __builtin_amdgcn_rcpf(1.0f + __builtin_amdgcn_exp2f(qv.y + mv.y)), S4.y);
        S4.z = fmaf(w.z, __builtin_amdgcn_rcpf(1.0f + __builtin_amdgcn_exp2f(qv.z + mv.z)), S4.z);
        S4.w = fmaf(w.w, __builtin_amdgcn_rcpf(1.0f + __builtin_amdgcn_exp2f(qv.w + mv.w)), S4.w);
      }
      float S = (S4.x + S4.y) + (S4.z + S4.w);
      int mi = m0 + s_ml;
      float p = row_valid ? ((mi < mlen) ? __builtin_amdgcn_exp2f(fmaf(-C2, S, c1)) : 0.f)
                          : 1.0f;
      reinterpret_cast<float*>(&pt4[t & 1][s_ml])[s_ii] = p;
      psum += p;
    }
    __syncthreads();   // all mt(t) reads done; pt4[t&1] ready

    // ---- write staged tile into mt ----
    if (do_stage) {
      int e0 = tid, e1 = tid + 256, e2 = tid + 512, e3 = tid + 768;
      mt[(e0 >> 6) * 64 + ((e0 & 63) ^ ((e0 >> 6) & 7))] = stg0;
      mt[(e1 >> 6) * 64 + ((e1 & 63) ^ ((e1 >> 6) & 7))] = stg1;
      mt[(e2 >> 6) * 64 + ((e2 & 63) ^ ((e2 >> 6) & 7))] = stg2;
      mt[(e3 >> 6) * 64 + ((e3 & 63) ^ ((e3 >> 6) & 7))] = stg3;
    }

    // ---- PV: packed fma; thread owns d-quad dq, wave owns 16 m's ----
    {
      const float* mpb = memb + (size_t)(m0 + wv_ * 16) * DM + dq * 4;
      #pragma unroll
      for (int mm = 0; mm < 16; ++mm) {
        float4 v  = *reinterpret_cast<const float4*>(mpb + (size_t)mm * DM);
        float4 pp = pt4[t & 1][wv_ * 16 + mm];   // wave-uniform broadcast
        float2v vx = {v.x, v.y}, vz = {v.z, v.w};
        float2v pxy = {pp.x, pp.y}, pzw = {pp.z, pp.w};
        a0x = pk_fma_bl(vx, pxy, a0x);  a0z = pk_fma_bl(vz, pxy, a0z);
        a1x = pk_fma_bh(vx, pxy, a1x);  a1z = pk_fma_bh(vz, pxy, a1z);
        a2x = pk_fma_bl(vx, pzw, a2x);  a2z = pk_fma_bl(vz, pzw, a2z);
        a3x = pk_fma_bh(vx, pzw, a3x);  a3z = pk_fma_bh(vz, pzw, a3z);
      }
    }
    __syncthreads();   // mt(t+1) staged; pt4[t&1] readers done
  }

  // ---- epilogue: per-row psum reduce + cross-wave output reduce ----
  {
    float s = psum;
    #pragma unroll
    for (int o = 32; o >= 1; o >>= 1) s += __shfl_xor(s, o);
    if (dq == 0) red[wv_] = s;
  }
  float4* osl = &mt[0];   // reuse 16KB tile LDS as [16][64] float4
  osl[(wv_ * 4 + 0) * 64 + dq] = make_float4(a0x.x, a0x.y, a0z.x, a0z.y);
  osl[(wv_ * 4 + 1) * 64 + dq] = make_float4(a1x.x, a1x.y, a1z.x, a1z.y);
  osl[(wv_ * 4 + 2) * 64 + dq] = make_float4(a2x.x, a2x.y, a2z.x, a2z.y);
  osl[(wv_ * 4 + 3) * 64 + dq] = make_float4(a3x.x, a3x.y, a3z.x, a3z.y);
  __syncthreads();

  {
    int ii = tid >> 6, d2 = tid & 63;
    float4 s = osl[ii * 64 + d2];
    #pragma unroll
    for (int w = 1; w < 4; ++w) {
      float4 v = osl[(w * 4 + ii) * 64 + d2];
      s.x += v.x; s.y += v.y; s.z += v.z; s.w += v.w;
    }
    size_t r = (size_t)b * Ti + i0 + ii;
    reinterpret_cast<float4*>(o_part)[((size_t)z * 2048 + r) * 64 + d2] = s;
  }
  if (tid < TI) {
    psum_part[(size_t)z * 2048 + (size_t)b * Ti + i0 + tid] = red[tid];
  }
}

// ---------------- Combine: out = sum_z o_part / sum_z psum
__global__ __launch_bounds__(256) void combine_kernel(
    const float* __restrict__ o_part, const float* __restrict__ psum_part,
    float* __restrict__ out, int nsplit)
{
  int e = blockIdx.x * 256 + threadIdx.x;   // float4 index
  int r = e >> 6;
  const float4* op4 = reinterpret_cast<const float4*>(o_part);
  float4 o = op4[e];
  float s = psum_part[r];
  if (nsplit == 2) {
    float4 o1 = op4[e + 131072];
    o.x += o1.x; o.y += o1.y; o.z += o1.z; o.w += o1.w;
    s += psum_part[r + 2048];
  }
  float inv = __builtin_amdgcn_rcpf(s);
  o.x *= inv; o.y *= inv; o.z *= inv; o.w *= inv;
  reinterpret_cast<float4*>(out)[e] = o;
}

extern "C" void kernel_launch(void* const* d_in, const int* in_sizes, int n_in,
                              void* d_out, int out_size, void* d_ws, size_t ws_size,
                              hipStream_t stream) {
  const float* inputs   = (const float*)d_in[0];  // (4,512,256)
  const float* memory   = (const float*)d_in[1];  // (4,1024,256)
  const int*   in_len   = (const int*)  d_in[2];  // (4)
  const int*   mem_len  = (const int*)  d_in[3];  // (4)
  const float* W_in     = (const float*)d_in[4];  // (64,256)
  const float* b_in     = (const float*)d_in[5];  // (64)
  const float* W_mem    = (const float*)d_in[6];  // (64,256)
  const float* W_final  = (const float*)d_in[7];  // (64)
  float* out = (float*)d_out;                     // (4,512,256)

  float* in_item   = (float*)d_ws;                  // 512 KB
  float* mem_itemT = in_item + 2048 * 64;           // 1 MB
  float* o_part    = mem_itemT + 4096 * 64;         // up to 4 MB
  float* psum_part = o_part + 2 * 2048 * 256;       // 16 KB

  size_t need2 = (size_t)(131072 + 262144 + 2 * 524288 + 2 * 2048 + 64) * 4;
  int nsplit = (ws_size >= need2) ? 2 : 1;

  proj_kernel<<<1536, 256, 0, stream>>>(inputs, memory, W_in, b_in, W_mem,
                                        in_item, mem_itemT);
  attn_kernel<<<dim3(512 * nsplit), 256, 0, stream>>>(
      in_item, mem_itemT, memory, in_len, mem_len, W_final,
      o_part, psum_part, 1024 / nsplit);
  combine_kernel<<<512, 256, 0, stream>>>(o_part, psum_part, out, nsplit);
}

// Round 9
// 114.897 us; speedup vs baseline: 1.0909x; 1.0909x over previous
//
#include <hip/hip_runtime.h>

#define C2  2.8853900817779268f   // 2*log2(e)
#define L2E 1.4426950408889634f   // log2(e)

typedef float float2v __attribute__((ext_vector_type(2)));

__device__ __forceinline__ float2v pk_fma(float2v a, float2v b, float2v c) {
  float2v d;
  asm("v_pk_fma_f32 %0, %1, %2, %3" : "=v"(d) : "v"(a), "v"(b), "v"(c));
  return d;
}
// d.lo = a.lo*b.lo + c.lo ; d.hi = a.hi*b.lo + c.hi   (broadcast b.lo)
__device__ __forceinline__ float2v pk_fma_bl(float2v a, float2v b, float2v c) {
  float2v d;
  asm("v_pk_fma_f32 %0, %1, %2, %3 op_sel:[0,0,0] op_sel_hi:[1,0,1]"
      : "=v"(d) : "v"(a), "v"(b), "v"(c));
  return d;
}
// d.lo = a.lo*b.hi + c.lo ; d.hi = a.hi*b.hi + c.hi   (broadcast b.hi)
__device__ __forceinline__ float2v pk_fma_bh(float2v a, float2v b, float2v c) {
  float2v d;
  asm("v_pk_fma_f32 %0, %1, %2, %3 op_sel:[0,1,0] op_sel_hi:[1,1,1]"
      : "=v"(d) : "v"(a), "v"(b), "v"(c));
  return d;
}

// ---------------- Projection (outputs PRE-SCALED by C2):
// block = 16 rows x 16 d; grid = 384 row-groups x 4 d-groups = 1536 blocks, 16KB LDS.
__global__ __launch_bounds__(256) void proj_kernel(
    const float* __restrict__ inputs, const float* __restrict__ memory,
    const float* __restrict__ W_in, const float* __restrict__ b_in,
    const float* __restrict__ W_mem,
    float* __restrict__ in_item, float* __restrict__ mem_itemT)
{
  const int NIN = 2048;
  int blk = blockIdx.x;
  int dg = blk & 3;
  int r0 = (blk >> 2) * 16;
  int tid = threadIdx.x;
  int dl = tid & 15;            // d within group
  int rw = tid >> 4;            // row within block (0..15)
  int d  = dg * 16 + dl;

  __shared__ float4 wlds[16][64];   // W rows [dg*16 .. dg*16+16), swizzled

  bool is_in = (r0 < NIN);
  const float* Wsel  = is_in ? W_in  : W_mem;
  const float* Abase = is_in ? inputs : memory;
  int ar0 = is_in ? r0 : r0 - NIN;

  const float4* Wv = reinterpret_cast<const float4*>(Wsel + (size_t)dg * 16 * 256);
  #pragma unroll
  for (int u = 0; u < 4; ++u) {
    int e = tid + u * 256;       // 0..1023
    int j = e >> 6, k4 = e & 63;
    wlds[j][k4 ^ (j & 7)] = Wv[e];
  }
  float bias = is_in ? b_in[d] : 0.f;
  __syncthreads();

  const float4* A0 = reinterpret_cast<const float4*>(Abase + (size_t)(ar0 + rw) * 256);
  float2v acc = {0.f, 0.f};
  #pragma unroll 8
  for (int k4 = 0; k4 < 64; ++k4) {
    float4 w = wlds[dl][k4 ^ (dl & 7)];
    float4 a = A0[k4];
    acc = pk_fma(float2v{a.x, a.y}, float2v{w.x, w.y}, acc);
    acc = pk_fma(float2v{a.z, a.w}, float2v{w.z, w.w}, acc);
  }
  float val = (acc.x + acc.y + bias) * C2;
  int row = ar0 + rw;
  if (is_in) {
    in_item[(size_t)row * 64 + d] = val;
  } else {
    int b_ = row >> 10, m = row & 1023;
    mem_itemT[((size_t)(b_ * 16 + (d >> 2)) * 1024 + m) * 4 + (d & 3)] = val;
  }
}

// ---------------- Fused score+softmax+PV over a Tm slice.
// 256 threads (4 waves), TI=4, MT=64, single 16KB linear tile buffer,
// late staging (no long-lived prefetch regs -> no spill), 2 barriers/tile.
__global__ __launch_bounds__(256, 6) void attn_kernel(
    const float* __restrict__ in_item,   // (B,Ti,64), pre-scaled
    const float* __restrict__ mem_itemT, // (B,16,Tm,4), pre-scaled, d-major
    const float* __restrict__ memory,    // (B,Tm,256)
    const int* __restrict__ in_len, const int* __restrict__ mem_len,
    const float* __restrict__ W_final,   // (64)
    float* __restrict__ o_part,          // (nsplit, B*Ti, 256)
    float* __restrict__ psum_part,       // (nsplit, B*Ti)
    int m_count)
{
  const int Ti = 512, Tm = 1024, DM = 256;
  const int TI = 4, MT = 64;
  const int NT = m_count >> 6;
  int lin = blockIdx.x;
  int b, z, it;
  if (m_count == 512) { b = lin & 3; z = (lin >> 2) & 1; it = lin >> 3; }
  else                { b = lin & 3; z = 0;              it = lin >> 2; }
  int i0 = it * TI;
  int m_begin = z * m_count;
  int tid = threadIdx.x;

  __shared__ float4 mt[16 * 64];     // mem_item tile, 16KB, LINEAR [d4][m]
  __shared__ float4 pt4[2][64];      // p transposed, dbuf, 2KB
  __shared__ float  red[4];

  const int s_ii = __builtin_amdgcn_readfirstlane(tid >> 6);  // wave-uniform row
  const int s_ml = tid & 63;
  const int dq = tid & 63, wv_ = tid >> 6;

  float4 qreg[16];   // wave-uniform -> SGPRs
  {
    const float4* qrow = reinterpret_cast<const float4*>(
        in_item + ((size_t)b * Ti + i0 + s_ii) * 64);
    #pragma unroll
    for (int j = 0; j < 16; ++j) qreg[j] = qrow[j];
  }

  float Wsum = 0.f;
  #pragma unroll
  for (int j = 0; j < 64; ++j) Wsum += W_final[j];   // uniform -> s_loads
  const float c1 = L2E * Wsum;
  const float4* Wf4 = reinterpret_cast<const float4*>(W_final);

  int ilen = in_len[b], mlen = mem_len[b];
  const bool row_valid = (i0 + s_ii) < ilen;

  const float4* mT4 = reinterpret_cast<const float4*>(mem_itemT);
  const int bb16 = b * 16;
  const float* memb = memory + (size_t)b * Tm * DM;

  float psum = 0.f;
  float2v a0x = {0,0}, a0z = {0,0}, a1x = {0,0}, a1z = {0,0};
  float2v a2x = {0,0}, a2z = {0,0}, a3x = {0,0}, a3z = {0,0};

  // ---- prologue: stage tile 0 (4 float4 per thread, coalesced, linear) ----
  #pragma unroll
  for (int u = 0; u < 4; ++u) {
    int e = tid + u * 256;
    int d4 = e >> 6, mm = e & 63;
    mt[d4 * 64 + mm] = mT4[(size_t)(bb16 + d4) * 1024 + m_begin + mm];
  }
  __syncthreads();

  #pragma unroll 1
  for (int t = 0; t < NT; ++t) {
    int m0 = m_begin + t * MT;

    // ---- score: LDS reads (conflict-free along m), q/w uniform ----
    {
      float4 S4 = make_float4(0.f, 0.f, 0.f, 0.f);
      #pragma unroll
      for (int d4 = 0; d4 < 16; ++d4) {
        float4 mv = mt[d4 * 64 + s_ml];
        float4 qv = qreg[d4];
        float4 w  = Wf4[d4];
        S4.x = fmaf(w.x, __builtin_amdgcn_rcpf(1.0f + __builtin_amdgcn_exp2f(qv.x + mv.x)), S4.x);
        S4.y = fmaf(w.y, __builtin_amdgcn_rcpf(1.0f + __builtin_amdgcn_exp2f(qv.y + mv.y)), S4.y);
        S4.z = fmaf(w.z, __builtin_amdgcn_rcpf(1.0f + __builtin_amdgcn_exp2f(qv.z + mv.z)), S4.z);
        S4.w = fmaf(w.w, __builtin_amdgcn_rcpf(1.0f + __builtin_amdgcn_exp2f(qv.w + mv.w)), S4.w);
      }
      float S = (S4.x + S4.y) + (S4.z + S4.w);
      int mi = m0 + s_ml;
      float p = row_valid ? ((mi < mlen) ? __builtin_amdgcn_exp2f(fmaf(-C2, S, c1)) : 0.f)
                          : 1.0f;
      reinterpret_cast<float*>(&pt4[t & 1][s_ml])[s_ii] = p;
      psum += p;
    }
    __syncthreads();   // (A) all mt(t) reads done; pt4[t&1] ready

    // ---- stage tile t+1 (short live range: load + immediate ds_write;
    //      scheduler overlaps the load latency with PV below) ----
    if (t + 1 < NT) {
      int mb = m_begin + (t + 1) * MT;
      #pragma unroll
      for (int u = 0; u < 4; ++u) {
        int e = tid + u * 256;
        int d4 = e >> 6, mm = e & 63;
        mt[d4 * 64 + mm] = mT4[(size_t)(bb16 + d4) * 1024 + mb + mm];
      }
    }

    // ---- PV: packed fma; thread owns d-quad dq, wave owns 16 m's ----
    {
      const float* mpb = memb + (size_t)(m0 + wv_ * 16) * DM + dq * 4;
      #pragma unroll
      for (int mm = 0; mm < 16; ++mm) {
        float4 v  = *reinterpret_cast<const float4*>(mpb + (size_t)mm * DM);
        float4 pp = pt4[t & 1][wv_ * 16 + mm];   // wave-uniform broadcast
        float2v vx = {v.x, v.y}, vz = {v.z, v.w};
        float2v pxy = {pp.x, pp.y}, pzw = {pp.z, pp.w};
        a0x = pk_fma_bl(vx, pxy, a0x);  a0z = pk_fma_bl(vz, pxy, a0z);
        a1x = pk_fma_bh(vx, pxy, a1x);  a1z = pk_fma_bh(vz, pxy, a1z);
        a2x = pk_fma_bl(vx, pzw, a2x);  a2z = pk_fma_bl(vz, pzw, a2z);
        a3x = pk_fma_bh(vx, pzw, a3x);  a3z = pk_fma_bh(vz, pzw, a3z);
      }
    }
    __syncthreads();   // (B) mt(t+1) written; safe for next score
  }

  // ---- epilogue: per-row psum reduce + cross-wave output reduce ----
  {
    float s = psum;
    #pragma unroll
    for (int o = 32; o >= 1; o >>= 1) s += __shfl_xor(s, o);
    if (dq == 0) red[wv_] = s;
  }
  float4* osl = &mt[0];   // reuse 16KB tile LDS as [16][64] float4
  osl[(wv_ * 4 + 0) * 64 + dq] = make_float4(a0x.x, a0x.y, a0z.x, a0z.y);
  osl[(wv_ * 4 + 1) * 64 + dq] = make_float4(a1x.x, a1x.y, a1z.x, a1z.y);
  osl[(wv_ * 4 + 2) * 64 + dq] = make_float4(a2x.x, a2x.y, a2z.x, a2z.y);
  osl[(wv_ * 4 + 3) * 64 + dq] = make_float4(a3x.x, a3x.y, a3z.x, a3z.y);
  __syncthreads();

  {
    int ii = tid >> 6, d2 = tid & 63;
    float4 s = osl[ii * 64 + d2];
    #pragma unroll
    for (int w = 1; w < 4; ++w) {
      float4 v = osl[(w * 4 + ii) * 64 + d2];
      s.x += v.x; s.y += v.y; s.z += v.z; s.w += v.w;
    }
    size_t r = (size_t)b * Ti + i0 + ii;
    reinterpret_cast<float4*>(o_part)[((size_t)z * 2048 + r) * 64 + d2] = s;
  }
  if (tid < TI) {
    psum_part[(size_t)z * 2048 + (size_t)b * Ti + i0 + tid] = red[tid];
  }
}

// ---------------- Combine: out = sum_z o_part / sum_z psum
__global__ __launch_bounds__(256) void combine_kernel(
    const float* __restrict__ o_part, const float* __restrict__ psum_part,
    float* __restrict__ out, int nsplit)
{
  int e = blockIdx.x * 256 + threadIdx.x;   // float4 index
  int r = e >> 6;
  const float4* op4 = reinterpret_cast<const float4*>(o_part);
  float4 o = op4[e];
  float s = psum_part[r];
  if (nsplit == 2) {
    float4 o1 = op4[e + 131072];
    o.x += o1.x; o.y += o1.y; o.z += o1.z; o.w += o1.w;
    s += psum_part[r + 2048];
  }
  float inv = __builtin_amdgcn_rcpf(s);
  o.x *= inv; o.y *= inv; o.z *= inv; o.w *= inv;
  reinterpret_cast<float4*>(out)[e] = o;
}

extern "C" void kernel_launch(void* const* d_in, const int* in_sizes, int n_in,
                              void* d_out, int out_size, void* d_ws, size_t ws_size,
                              hipStream_t stream) {
  const float* inputs   = (const float*)d_in[0];  // (4,512,256)
  const float* memory   = (const float*)d_in[1];  // (4,1024,256)
  const int*   in_len   = (const int*)  d_in[2];  // (4)
  const int*   mem_len  = (const int*)  d_in[3];  // (4)
  const float* W_in     = (const float*)d_in[4];  // (64,256)
  const float* b_in     = (const float*)d_in[5];  // (64)
  const float* W_mem    = (const float*)d_in[6];  // (64,256)
  const float* W_final  = (const float*)d_in[7];  // (64)
  float* out = (float*)d_out;                     // (4,512,256)

  float* in_item   = (float*)d_ws;                  // 512 KB
  float* mem_itemT = in_item + 2048 * 64;           // 1 MB
  float* o_part    = mem_itemT + 4096 * 64;         // up to 4 MB
  float* psum_part = o_part + 2 * 2048 * 256;       // 16 KB

  size_t need2 = (size_t)(131072 + 262144 + 2 * 524288 + 2 * 2048 + 64) * 4;
  int nsplit = (ws_size >= need2) ? 2 : 1;

  proj_kernel<<<1536, 256, 0, stream>>>(inputs, memory, W_in, b_in, W_mem,
                                        in_item, mem_itemT);
  attn_kernel<<<dim3(512 * nsplit), 256, 0, stream>>>(
      in_item, mem_itemT, memory, in_len, mem_len, W_final,
      o_part, psum_part, 1024 / nsplit);
  combine_kernel<<<512, 256, 0, stream>>>(o_part, psum_part, out, nsplit);
}

// Round 10
// 76.129 us; speedup vs baseline: 1.6464x; 1.5092x over previous
//
#include <hip/hip_runtime.h>

#define C2  2.8853900817779268f   // 2*log2(e)
#define L2E 1.4426950408889634f   // log2(e)

typedef float float2v __attribute__((ext_vector_type(2)));

__device__ __forceinline__ float2v pk_fma(float2v a, float2v b, float2v c) {
  float2v d;
  asm("v_pk_fma_f32 %0, %1, %2, %3" : "=v"(d) : "v"(a), "v"(b), "v"(c));
  return d;
}
// d.lo = a.lo*b.lo + c.lo ; d.hi = a.hi*b.lo + c.hi   (broadcast b.lo)
__device__ __forceinline__ float2v pk_fma_bl(float2v a, float2v b, float2v c) {
  float2v d;
  asm("v_pk_fma_f32 %0, %1, %2, %3 op_sel:[0,0,0] op_sel_hi:[1,0,1]"
      : "=v"(d) : "v"(a), "v"(b), "v"(c));
  return d;
}
// d.lo = a.lo*b.hi + c.lo ; d.hi = a.hi*b.hi + c.hi   (broadcast b.hi)
__device__ __forceinline__ float2v pk_fma_bh(float2v a, float2v b, float2v c) {
  float2v d;
  asm("v_pk_fma_f32 %0, %1, %2, %3 op_sel:[0,1,0] op_sel_hi:[1,1,1]"
      : "=v"(d) : "v"(a), "v"(b), "v"(c));
  return d;
}

// ---------------- Projection (outputs PRE-SCALED by C2):
// block = 16 rows x 16 d; grid = 384 row-groups x 4 d-groups = 1536 blocks, 16KB LDS.
__global__ __launch_bounds__(256) void proj_kernel(
    const float* __restrict__ inputs, const float* __restrict__ memory,
    const float* __restrict__ W_in, const float* __restrict__ b_in,
    const float* __restrict__ W_mem,
    float* __restrict__ in_item, float* __restrict__ mem_itemT)
{
  const int NIN = 2048;
  int blk = blockIdx.x;
  int dg = blk & 3;
  int r0 = (blk >> 2) * 16;
  int tid = threadIdx.x;
  int dl = tid & 15;            // d within group
  int rw = tid >> 4;            // row within block (0..15)
  int d  = dg * 16 + dl;

  __shared__ float4 wlds[16][64];   // W rows [dg*16 .. dg*16+16), swizzled

  bool is_in = (r0 < NIN);
  const float* Wsel  = is_in ? W_in  : W_mem;
  const float* Abase = is_in ? inputs : memory;
  int ar0 = is_in ? r0 : r0 - NIN;

  const float4* Wv = reinterpret_cast<const float4*>(Wsel + (size_t)dg * 16 * 256);
  #pragma unroll
  for (int u = 0; u < 4; ++u) {
    int e = tid + u * 256;       // 0..1023
    int j = e >> 6, k4 = e & 63;
    wlds[j][k4 ^ (j & 7)] = Wv[e];
  }
  float bias = is_in ? b_in[d] : 0.f;
  __syncthreads();

  const float4* A0 = reinterpret_cast<const float4*>(Abase + (size_t)(ar0 + rw) * 256);
  float2v acc = {0.f, 0.f};
  #pragma unroll 8
  for (int k4 = 0; k4 < 64; ++k4) {
    float4 w = wlds[dl][k4 ^ (dl & 7)];
    float4 a = A0[k4];
    acc = pk_fma(float2v{a.x, a.y}, float2v{w.x, w.y}, acc);
    acc = pk_fma(float2v{a.z, a.w}, float2v{w.z, w.w}, acc);
  }
  float val = (acc.x + acc.y + bias) * C2;
  int row = ar0 + rw;
  if (is_in) {
    in_item[(size_t)row * 64 + d] = val;
  } else {
    int b_ = row >> 10, m = row & 1023;
    mem_itemT[((size_t)(b_ * 16 + (d >> 2)) * 1024 + m) * 4 + (d & 3)] = val;
  }
}

// ---------------- Fused score+softmax+PV over a Tm slice.
// 256 threads (4 waves), TI=4, MT=64, single 16KB linear tile buffer,
// q in LDS (broadcast reads) -> ~48 natural VGPRs, no spill, 8 blocks/CU.
__global__ __launch_bounds__(256, 4) void attn_kernel(
    const float* __restrict__ in_item,   // (B,Ti,64), pre-scaled
    const float* __restrict__ mem_itemT, // (B,16,Tm,4), pre-scaled, d-major
    const float* __restrict__ memory,    // (B,Tm,256)
    const int* __restrict__ in_len, const int* __restrict__ mem_len,
    const float* __restrict__ W_final,   // (64)
    float* __restrict__ o_part,          // (nsplit, B*Ti, 256)
    float* __restrict__ psum_part,       // (nsplit, B*Ti)
    int m_count)
{
  const int Ti = 512, Tm = 1024, DM = 256;
  const int TI = 4, MT = 64;
  const int NT = m_count >> 6;
  int lin = blockIdx.x;
  int b, z, it;
  if (m_count == 512) { b = lin & 3; z = (lin >> 2) & 1; it = lin >> 3; }
  else                { b = lin & 3; z = 0;              it = lin >> 2; }
  int i0 = it * TI;
  int m_begin = z * m_count;
  int tid = threadIdx.x;

  __shared__ float4 mt[16 * 64];     // mem_item tile, 16KB, LINEAR [d4][m]
  __shared__ float4 pt4[2][64];      // p transposed, dbuf, 2KB
  __shared__ float  qs[TI][64];      // q rows, 1KB (uniform-address broadcast reads)
  __shared__ float  red[4];

  const int s_ii = __builtin_amdgcn_readfirstlane(tid >> 6);  // wave-uniform row
  const int s_ml = tid & 63;
  const int dq = tid & 63, wv_ = tid >> 6;

  // q rows -> LDS (one float per thread)
  qs[tid >> 6][tid & 63] = in_item[((size_t)b * Ti + i0 + (tid >> 6)) * 64 + (tid & 63)];

  float Wsum = 0.f;
  #pragma unroll
  for (int j = 0; j < 64; ++j) Wsum += W_final[j];   // uniform -> s_loads
  const float c1 = L2E * Wsum;
  const float4* Wf4 = reinterpret_cast<const float4*>(W_final);

  int ilen = in_len[b], mlen = mem_len[b];
  const bool row_valid = (i0 + s_ii) < ilen;

  const float4* mT4 = reinterpret_cast<const float4*>(mem_itemT);
  const int bb16 = b * 16;
  const float* memb = memory + (size_t)b * Tm * DM;

  float psum = 0.f;
  float2v a0x = {0,0}, a0z = {0,0}, a1x = {0,0}, a1z = {0,0};
  float2v a2x = {0,0}, a2z = {0,0}, a3x = {0,0}, a3z = {0,0};

  // ---- prologue: stage tile 0 (4 float4 per thread, coalesced, linear) ----
  #pragma unroll
  for (int u = 0; u < 4; ++u) {
    int e = tid + u * 256;
    int d4 = e >> 6, mm = e & 63;
    mt[d4 * 64 + mm] = mT4[(size_t)(bb16 + d4) * 1024 + m_begin + mm];
  }
  __syncthreads();

  const float4* qrow4 = reinterpret_cast<const float4*>(qs[s_ii]);

  #pragma unroll 1
  for (int t = 0; t < NT; ++t) {
    int m0 = m_begin + t * MT;

    // ---- score: LDS reads (tile along m: conflict-free; q: broadcast) ----
    {
      float4 S4 = make_float4(0.f, 0.f, 0.f, 0.f);
      #pragma unroll
      for (int d4 = 0; d4 < 16; ++d4) {
        float4 mv = mt[d4 * 64 + s_ml];
        float4 qv = qrow4[d4];
        float4 w  = Wf4[d4];
        S4.x = fmaf(w.x, __builtin_amdgcn_rcpf(1.0f + __builtin_amdgcn_exp2f(qv.x + mv.x)), S4.x);
        S4.y = fmaf(w.y, __builtin_amdgcn_rcpf(1.0f + __builtin_amdgcn_exp2f(qv.y + mv.y)), S4.y);
        S4.z = fmaf(w.z, __builtin_amdgcn_rcpf(1.0f + __builtin_amdgcn_exp2f(qv.z + mv.z)), S4.z);
        S4.w = fmaf(w.w, __builtin_amdgcn_rcpf(1.0f + __builtin_amdgcn_exp2f(qv.w + mv.w)), S4.w);
      }
      float S = (S4.x + S4.y) + (S4.z + S4.w);
      int mi = m0 + s_ml;
      float p = row_valid ? ((mi < mlen) ? __builtin_amdgcn_exp2f(fmaf(-C2, S, c1)) : 0.f)
                          : 1.0f;
      reinterpret_cast<float*>(&pt4[t & 1][s_ml])[s_ii] = p;
      psum += p;
    }
    __syncthreads();   // (A) all mt(t) reads done; pt4[t&1] ready

    // ---- stage tile t+1 (short live range: load + immediate ds_write) ----
    if (t + 1 < NT) {
      int mb = m_begin + (t + 1) * MT;
      #pragma unroll
      for (int u = 0; u < 4; ++u) {
        int e = tid + u * 256;
        int d4 = e >> 6, mm = e & 63;
        mt[d4 * 64 + mm] = mT4[(size_t)(bb16 + d4) * 1024 + mb + mm];
      }
    }

    // ---- PV: packed fma; thread owns d-quad dq, wave owns 16 m's ----
    {
      const float* mpb = memb + (size_t)(m0 + wv_ * 16) * DM + dq * 4;
      #pragma unroll
      for (int mm = 0; mm < 16; ++mm) {
        float4 v  = *reinterpret_cast<const float4*>(mpb + (size_t)mm * DM);
        float4 pp = pt4[t & 1][wv_ * 16 + mm];   // wave-uniform broadcast
        float2v vx = {v.x, v.y}, vz = {v.z, v.w};
        float2v pxy = {pp.x, pp.y}, pzw = {pp.z, pp.w};
        a0x = pk_fma_bl(vx, pxy, a0x);  a0z = pk_fma_bl(vz, pxy, a0z);
        a1x = pk_fma_bh(vx, pxy, a1x);  a1z = pk_fma_bh(vz, pxy, a1z);
        a2x = pk_fma_bl(vx, pzw, a2x);  a2z = pk_fma_bl(vz, pzw, a2z);
        a3x = pk_fma_bh(vx, pzw, a3x);  a3z = pk_fma_bh(vz, pzw, a3z);
      }
    }
    __syncthreads();   // (B) mt(t+1) written; safe for next score
  }

  // ---- epilogue: per-row psum reduce + cross-wave output reduce ----
  {
    float s = psum;
    #pragma unroll
    for (int o = 32; o >= 1; o >>= 1) s += __shfl_xor(s, o);
    if (dq == 0) red[wv_] = s;
  }
  float4* osl = &mt[0];   // reuse 16KB tile LDS as [16][64] float4
  osl[(wv_ * 4 + 0) * 64 + dq] = make_float4(a0x.x, a0x.y, a0z.x, a0z.y);
  osl[(wv_ * 4 + 1) * 64 + dq] = make_float4(a1x.x, a1x.y, a1z.x, a1z.y);
  osl[(wv_ * 4 + 2) * 64 + dq] = make_float4(a2x.x, a2x.y, a2z.x, a2z.y);
  osl[(wv_ * 4 + 3) * 64 + dq] = make_float4(a3x.x, a3x.y, a3z.x, a3z.y);
  __syncthreads();

  {
    int ii = tid >> 6, d2 = tid & 63;
    float4 s = osl[ii * 64 + d2];
    #pragma unroll
    for (int w = 1; w < 4; ++w) {
      float4 v = osl[(w * 4 + ii) * 64 + d2];
      s.x += v.x; s.y += v.y; s.z += v.z; s.w += v.w;
    }
    size_t r = (size_t)b * Ti + i0 + ii;
    reinterpret_cast<float4*>(o_part)[((size_t)z * 2048 + r) * 64 + d2] = s;
  }
  if (tid < TI) {
    psum_part[(size_t)z * 2048 + (size_t)b * Ti + i0 + tid] = red[tid];
  }
}

// ---------------- Combine: out = sum_z o_part / sum_z psum
__global__ __launch_bounds__(256) void combine_kernel(
    const float* __restrict__ o_part, const float* __restrict__ psum_part,
    float* __restrict__ out, int nsplit)
{
  int e = blockIdx.x * 256 + threadIdx.x;   // float4 index
  int r = e >> 6;
  const float4* op4 = reinterpret_cast<const float4*>(o_part);
  float4 o = op4[e];
  float s = psum_part[r];
  if (nsplit == 2) {
    float4 o1 = op4[e + 131072];
    o.x += o1.x; o.y += o1.y; o.z += o1.z; o.w += o1.w;
    s += psum_part[r + 2048];
  }
  float inv = __builtin_amdgcn_rcpf(s);
  o.x *= inv; o.y *= inv; o.z *= inv; o.w *= inv;
  reinterpret_cast<float4*>(out)[e] = o;
}

extern "C" void kernel_launch(void* const* d_in, const int* in_sizes, int n_in,
                              void* d_out, int out_size, void* d_ws, size_t ws_size,
                              hipStream_t stream) {
  const float* inputs   = (const float*)d_in[0];  // (4,512,256)
  const float* memory   = (const float*)d_in[1];  // (4,1024,256)
  const int*   in_len   = (const int*)  d_in[2];  // (4)
  const int*   mem_len  = (const int*)  d_in[3];  // (4)
  const float* W_in     = (const float*)d_in[4];  // (64,256)
  const float* b_in     = (const float*)d_in[5];  // (64)
  const float* W_mem    = (const float*)d_in[6];  // (64,256)
  const float* W_final  = (const float*)d_in[7];  // (64)
  float* out = (float*)d_out;                     // (4,512,256)

  float* in_item   = (float*)d_ws;                  // 512 KB
  float* mem_itemT = in_item + 2048 * 64;           // 1 MB
  float* o_part    = mem_itemT + 4096 * 64;         // up to 4 MB
  float* psum_part = o_part + 2 * 2048 * 256;       // 16 KB

  size_t need2 = (size_t)(131072 + 262144 + 2 * 524288 + 2 * 2048 + 64) * 4;
  int nsplit = (ws_size >= need2) ? 2 : 1;

  proj_kernel<<<1536, 256, 0, stream>>>(inputs, memory, W_in, b_in, W_mem,
                                        in_item, mem_itemT);
  attn_kernel<<<dim3(512 * nsplit), 256, 0, stream>>>(
      in_item, mem_itemT, memory, in_len, mem_len, W_final,
      o_part, psum_part, 1024 / nsplit);
  combine_kernel<<<512, 256, 0, stream>>>(o_part, psum_part, out, nsplit);
}